// Round 12
// baseline (103.813 us; speedup 1.0000x reference)
//
#include <hip/hip_runtime.h>
#include <cstddef>

#define BH 4
#define CH 64
#define OH 64
#define HH 128
#define WW 128
#define KK 9
#define HW (HH * WW)     // 16384

#define HX 4             // x halo (symmetric)
#define HYT 4            // y halo above (rows -4..+11 relative to y0)
#define TW 25            // tile cols  (16 + 2*4 + 1)
#define TH 16            // tile rows  (8 + 4 above + 4 below)
#define NREC (TW * TH)   // 400 pixel records in LDS (51.2 KB)
#define NCHUNK (NREC * 8)   // 3200 16-B staging chunks

typedef __attribute__((ext_vector_type(8))) short short8;       // 8 bf16
typedef __attribute__((ext_vector_type(4))) float f32x4;        // MFMA acc
typedef __attribute__((ext_vector_type(2))) float f32x2;
typedef __attribute__((ext_vector_type(4))) unsigned int uint4v;
typedef __attribute__((ext_vector_type(8))) unsigned short ushort8v;

__device__ __forceinline__ unsigned short f2bf(float f) {
    unsigned u = __float_as_uint(f);
    u += 0x7fffu + ((u >> 16) & 1u);   // RNE
    return (unsigned short)(u >> 16);
}
__device__ __forceinline__ f32x2 bf2x2(unsigned d) {
    f32x2 r;
    r.x = __uint_as_float(d << 16);
    r.y = __uint_as_float(d & 0xffff0000u);
    return r;
}
__device__ __forceinline__ unsigned pack_bf2(f32x2 v) {
    unsigned u0 = __float_as_uint(v.x);
    u0 += 0x7fffu + ((u0 >> 16) & 1u);
    unsigned u1 = __float_as_uint(v.y);
    u1 += 0x7fffu + ((u1 >> 16) & 1u);
    return __builtin_amdgcn_perm(u1, u0, 0x07060302);
}
__device__ __forceinline__ uint4v combine4(uint4v c00, uint4v c10, uint4v c01, uint4v c11,
                                           float w00, float w10, float w01, float w11) {
    f32x2 W00 = {w00, w00}, W10 = {w10, w10}, W01 = {w01, w01}, W11 = {w11, w11};
    uint4v r;
#pragma unroll
    for (int j = 0; j < 4; ++j) {
        f32x2 s = W00 * bf2x2(c00[j]) + W10 * bf2x2(c10[j])
                + W01 * bf2x2(c01[j]) + W11 * bf2x2(c11[j]);
        r[j] = pack_bf2(s);
    }
    return r;
}

struct ABfrag { short8 aa, ab; };

// Gather + bilinear-combine one pixel row's A fragments from the LDS tile
// (global fallback for out-of-halo offsets).
__device__ __forceinline__ ABfrag gather_row(
        const uint4v* sv, const char* xtb, int b, int x0, int y0,
        float pxf, float pyf, float ox, float oy, int quad) {
    float fx = pxf + ox;
    float fy = pyf + oy;
    float x0f = floorf(fx), y0f = floorf(fy);
    float wx1 = fx - x0f, wy1 = fy - y0f;
    float wx0 = 1.0f - wx1, wy0 = 1.0f - wy1;
    int ix0 = (int)x0f, iy0 = (int)y0f;
    int ix1 = ix0 + 1, iy1 = iy0 + 1;
    bool vx0 = (unsigned)ix0 < (unsigned)WW;
    bool vx1 = (unsigned)ix1 < (unsigned)WW;
    bool vy0 = (unsigned)iy0 < (unsigned)HH;
    bool vy1 = (unsigned)iy1 < (unsigned)HH;
    float w00 = (vx0 && vy0) ? wx0 * wy0 : 0.0f;
    float w10 = (vx1 && vy0) ? wx1 * wy0 : 0.0f;
    float w01 = (vx0 && vy1) ? wx0 * wy1 : 0.0f;
    float w11 = (vx1 && vy1) ? wx1 * wy1 : 0.0f;
    int cx0 = min(max(ix0, 0), WW - 1), cx1 = min(max(ix1, 0), WW - 1);
    int cy0 = min(max(iy0, 0), HH - 1), cy1 = min(max(iy1, 0), HH - 1);

    int lc0 = cx0 - x0 + HX, lc1 = cx1 - x0 + HX;
    int lr0 = cy0 - y0 + HYT, lr1 = cy1 - y0 + HYT;
    bool oof = ((unsigned)lc0 > (TW - 1)) | ((unsigned)lc1 > (TW - 1)) |
               ((unsigned)lr0 > (TH - 1)) | ((unsigned)lr1 > (TH - 1));
    int sc0 = min(max(lc0, 0), TW - 1), sc1 = min(max(lc1, 0), TW - 1);
    int sr0 = min(max(lr0, 0), TH - 1), sr1 = min(max(lr1, 0), TH - 1);
    int p00 = sr0 * TW + sc0, p10 = sr0 * TW + sc1;
    int p01 = sr1 * TW + sc0, p11 = sr1 * TW + sc1;

    uint4v c00a = sv[p00 * 8 + ((quad + (p00 & 7)) & 7)];
    uint4v c00b = sv[p00 * 8 + ((quad + 4 + (p00 & 7)) & 7)];
    uint4v c10a = sv[p10 * 8 + ((quad + (p10 & 7)) & 7)];
    uint4v c10b = sv[p10 * 8 + ((quad + 4 + (p10 & 7)) & 7)];
    uint4v c01a = sv[p01 * 8 + ((quad + (p01 & 7)) & 7)];
    uint4v c01b = sv[p01 * 8 + ((quad + 4 + (p01 & 7)) & 7)];
    uint4v c11a = sv[p11 * 8 + ((quad + (p11 & 7)) & 7)];
    uint4v c11b = sv[p11 * 8 + ((quad + 4 + (p11 & 7)) & 7)];

    if (__builtin_expect(oof, 0)) {   // rare: genuinely large offsets
        int qoff = quad * 16;
        int base = b << 14;
        int o00 = ((base + (cy0 << 7) + cx0) << 7) + qoff;
        int o10 = ((base + (cy0 << 7) + cx1) << 7) + qoff;
        int o01 = ((base + (cy1 << 7) + cx0) << 7) + qoff;
        int o11 = ((base + (cy1 << 7) + cx1) << 7) + qoff;
        c00a = *(const uint4v*)(xtb + o00);
        c00b = *(const uint4v*)(xtb + o00 + 64);
        c10a = *(const uint4v*)(xtb + o10);
        c10b = *(const uint4v*)(xtb + o10 + 64);
        c01a = *(const uint4v*)(xtb + o01);
        c01b = *(const uint4v*)(xtb + o01 + 64);
        c11a = *(const uint4v*)(xtb + o11);
        c11b = *(const uint4v*)(xtb + o11 + 64);
    }

    ABfrag r;
    r.aa = __builtin_bit_cast(short8, combine4(c00a, c10a, c01a, c11a, w00, w10, w01, w11));
    r.ab = __builtin_bit_cast(short8, combine4(c00b, c10b, c01b, c11b, w00, w10, w01, w11));
    return r;
}

// ---------------------------------------------------------------------------
// Fused prep: blocks 0..1023 transpose x NCHW f32 -> NHWC bf16 (float4 loads,
// ushort8 stores); blocks 1024..1167 pack weight into MFMA B fragments.
// ---------------------------------------------------------------------------
__global__ __launch_bounds__(256) void dcl_prep(const float* __restrict__ x,
                                                const float* __restrict__ wgt,
                                                unsigned short* __restrict__ xt,
                                                unsigned short* __restrict__ wtb) {
    if (blockIdx.x < 1024) {
        __shared__ float tile[64][68];   // stride 68: float4-aligned, bank-benign
        int chunk = blockIdx.x;
        int b = chunk >> 8;
        int hw0 = (chunk & 255) * 64;
        int tid = threadIdx.x;           // 0..255
        int cg = tid >> 4;               // 0..15
        int tx4 = (tid & 15) * 4;        // 0,4,..,60
        const float* xb = x + (size_t)b * CH * HW + hw0;
#pragma unroll
        for (int pass = 0; pass < 4; ++pass) {
            int c = pass * 16 + cg;
            float4 v = *(const float4*)(xb + (size_t)c * HW + tx4);
            *(float4*)&tile[c][tx4] = v;
        }
        __syncthreads();
        unsigned short* xtb = xt + ((size_t)b << 20) + (size_t)hw0 * CH;
        int c8 = (tid & 7) * 8;
        int p0 = tid >> 3;               // 0..31
#pragma unroll
        for (int it = 0; it < 2; ++it) {
            int pxl = p0 + it * 32;
            ushort8v v;
#pragma unroll
            for (int j = 0; j < 8; ++j) v[j] = f2bf(tile[c8 + j][pxl]);
            *(ushort8v*)(xtb + (size_t)pxl * CH + c8) = v;
        }
    } else {
        // wpack: lane l of frag (ks,nt) holds B[k][n], k=ks*32+(l>>4)*8+j,
        // n=nt*16+(l&15), k=t*64+c.  addr: wtb[((ks*4+nt)*64+l)*8+j]
        int idx = (blockIdx.x - 1024) * 256 + threadIdx.x;   // 0..36863
        int j  = idx & 7;
        int l  = (idx >> 3) & 63;
        int nt = (idx >> 9) & 3;
        int ks = idx >> 11;
        int k = ks * 32 + ((l >> 4) * 8) + j;
        int n = nt * 16 + (l & 15);
        int c = k & 63;
        int t = k >> 6;
        wtb[idx] = f2bf(wgt[(n * CH + c) * KK + t]);
    }
}

// ---------------------------------------------------------------------------
// Main: block = 4 waves over a 16x8 px tile (512 blocks); each wave owns
// M=32 (two pixel rows 2w, 2w+1) x all 64 outputs. The 8 B-fragment loads
// per tap are shared across both A-tiles -> device B-L2 traffic halves
// (295 -> 147 MB), the largest pipe in R11's main. Tile + halo (25x16,
// 51.2 KB) staged to LDS once (coalesced, swizzled). Per-px VALU/LDS/MFMA
// unchanged vs R11. ONE barrier before the tap loop.
// ---------------------------------------------------------------------------
__global__ __launch_bounds__(256, 3) void dcl_main(
        const unsigned short* __restrict__ xt,   // [b][h][w][c] bf16
        const float* __restrict__ offset,
        const unsigned short* __restrict__ wtb,  // packed B fragments (72 KB)
        const float* __restrict__ bias,
        float* __restrict__ out) {
    __shared__ __align__(16) int smem[NREC * 32];   // 51200 B
    int tid = threadIdx.x;          // 0..255
    int lane = tid & 63;
    int wave = tid >> 6;            // 0..3

    // 16x8 pixel tile: 8 x-tiles, 16 y-tiles per image
    int b  = blockIdx.x >> 7;
    int t7 = blockIdx.x & 127;
    int x0 = (t7 & 7) << 4;
    int y0 = (t7 >> 3) << 3;
    int m = lane & 15;
    int quad = lane >> 4;
    int row0 = y0 + 2 * wave;       // this wave's first pixel row
    int pm = x0 + m;                // this lane's pixel x

    const char* xtb = (const char*)xt;
    const char* xim = xtb + (((size_t)b << 14) << 7);   // image base (bytes)
    const float* ob0 = offset + (((size_t)(b * 18)) << 14) + (row0 << 7) + pm;
    const float* ob1 = ob0 + WW;    // row0+1
    float pxf = (float)pm;
    float py0 = (float)row0;
    float py1 = py0 + 1.0f;

    // ---- stage pixel tile + halo into LDS (coalesced, swizzled) ----
    uint4v* sv = (uint4v*)smem;
#pragma unroll
    for (int i = 0; i < 13; ++i) {
        int id = tid + i * 256;
        if (id < NCHUNK) {
            int p = id >> 3, sub = id & 7;
            int r = p / TW, col = p - r * TW;
            int sy = min(max(y0 - HYT + r, 0), HH - 1);
            int sx = min(max(x0 - HX + col, 0), WW - 1);
            uint4v v = *(const uint4v*)(xim + (((sy << 7) + sx) << 7) + (sub << 4));
            sv[p * 8 + ((sub + (p & 7)) & 7)] = v;
        }
    }

    f32x4 acc0[4], acc1[4];
#pragma unroll
    for (int i = 0; i < 4; ++i) { acc0[i] = (f32x4)(0.f); acc1[i] = (f32x4)(0.f); }

    const short8* bfrags = (const short8*)wtb;

    __syncthreads();                // tile visible; only pre-epilogue barrier

    // ---- 9 taps, fully unrolled, barrier-free ----
#pragma unroll
    for (int t = 0; t < 9; ++t) {
        float ox0 = ob0[(size_t)(2 * t) << 14];
        float oy0 = ob0[(size_t)(2 * t + 1) << 14];
        float ox1 = ob1[(size_t)(2 * t) << 14];
        float oy1 = ob1[(size_t)(2 * t + 1) << 14];

        ABfrag r0 = gather_row(sv, xtb, b, x0, y0, pxf, py0, ox0, oy0, quad);
        ABfrag r1 = gather_row(sv, xtb, b, x0, y0, pxf, py1, ox1, oy1, quad);

        int ks = 2 * t;
        short8 bv0[4], bv1[4];
#pragma unroll
        for (int nt = 0; nt < 4; ++nt) {
            bv0[nt] = bfrags[(ks * 4 + nt) * 64 + lane];
            bv1[nt] = bfrags[((ks + 1) * 4 + nt) * 64 + lane];
        }
#pragma unroll
        for (int nt = 0; nt < 4; ++nt) {
            acc0[nt] = __builtin_amdgcn_mfma_f32_16x16x32_bf16(r0.aa, bv0[nt], acc0[nt], 0, 0, 0);
            acc0[nt] = __builtin_amdgcn_mfma_f32_16x16x32_bf16(r0.ab, bv1[nt], acc0[nt], 0, 0, 0);
            acc1[nt] = __builtin_amdgcn_mfma_f32_16x16x32_bf16(r1.aa, bv0[nt], acc1[nt], 0, 0, 0);
            acc1[nt] = __builtin_amdgcn_mfma_f32_16x16x32_bf16(r1.ab, bv1[nt], acc1[nt], 0, 0, 0);
        }
    }

    // ---- epilogue: C tiles -> LDS (reuse tile area), coalesced store ----
    __syncthreads();
    float* o_w = (float*)smem + wave * 2080;    // [p_local 0..31][o], stride 65
#pragma unroll
    for (int nt = 0; nt < 4; ++nt)
#pragma unroll
        for (int reg = 0; reg < 4; ++reg) {
            o_w[(quad * 4 + reg) * 65 + nt * 16 + m]        = acc0[nt][reg];
            o_w[(16 + quad * 4 + reg) * 65 + nt * 16 + m]   = acc1[nt][reg];
        }
    __syncthreads();

    const float* os = (const float*)smem;
#pragma unroll
    for (int j = tid; j < 64 * 128; j += 256) {
        int o = j >> 7;                  // wave-uniform per iteration
        int p = j & 127;
        int w2 = p >> 5, pi = p & 31;
        int a = pi >> 4, xx = pi & 15;
        int row = y0 + 2 * w2 + a;
        float v = os[w2 * 2080 + pi * 65 + o] + bias[o];
        out[(((size_t)(b * OH + o)) << 14) + (row << 7) + x0 + xx] = v;
    }
}

extern "C" void kernel_launch(void* const* d_in, const int* in_sizes, int n_in,
                              void* d_out, int out_size, void* d_ws, size_t ws_size,
                              hipStream_t stream) {
    const float* x      = (const float*)d_in[0];
    const float* offset = (const float*)d_in[1];
    const float* weight = (const float*)d_in[2];
    const float* bias   = (const float*)d_in[3];
    float* out = (float*)d_out;

    unsigned short* xt  = (unsigned short*)d_ws;                           // 8.39 MB
    unsigned short* wtb = (unsigned short*)((char*)d_ws + (size_t)BH * HW * CH * 2);

    dcl_prep<<<1024 + 144, 256, 0, stream>>>(x, weight, xt, wtb);
    dcl_main<<<(BH * HW) / 128, 256, 0, stream>>>(xt, offset, wtb, bias, out);
}

// Round 13
// 101.450 us; speedup vs baseline: 1.0233x; 1.0233x over previous
//
#include <hip/hip_runtime.h>
#include <cstddef>

#define BH 4
#define CH 64
#define OH 64
#define HH 128
#define WW 128
#define KK 9
#define HW (HH * WW)     // 16384

#define HX 4             // x halo (symmetric)
#define HYT 4            // y halo above
#define TW 25            // tile cols  (16 + 2*4 + 1)
#define TH 12            // tile rows  (4 + 4 above + 4 below, asym: -4..+7)
#define NREC (TW * TH)   // 300 pixel records in LDS (38.4 KB -> 4 blocks/CU)
#define NCHUNK (NREC * 8)   // 2400 16-B staging chunks

typedef __attribute__((ext_vector_type(8))) short short8;       // 8 bf16
typedef __attribute__((ext_vector_type(4))) float f32x4;        // MFMA acc
typedef __attribute__((ext_vector_type(2))) float f32x2;
typedef __attribute__((ext_vector_type(4))) unsigned int uint4v;
typedef __attribute__((ext_vector_type(8))) unsigned short ushort8v;

__device__ __forceinline__ unsigned short f2bf(float f) {
    unsigned u = __float_as_uint(f);
    u += 0x7fffu + ((u >> 16) & 1u);   // RNE
    return (unsigned short)(u >> 16);
}
__device__ __forceinline__ f32x2 bf2x2(unsigned d) {
    f32x2 r;
    r.x = __uint_as_float(d << 16);
    r.y = __uint_as_float(d & 0xffff0000u);
    return r;
}
__device__ __forceinline__ unsigned pack_bf2(f32x2 v) {
    unsigned u0 = __float_as_uint(v.x);
    u0 += 0x7fffu + ((u0 >> 16) & 1u);
    unsigned u1 = __float_as_uint(v.y);
    u1 += 0x7fffu + ((u1 >> 16) & 1u);
    return __builtin_amdgcn_perm(u1, u0, 0x07060302);
}
__device__ __forceinline__ uint4v combine4(uint4v c00, uint4v c10, uint4v c01, uint4v c11,
                                           float w00, float w10, float w01, float w11) {
    f32x2 W00 = {w00, w00}, W10 = {w10, w10}, W01 = {w01, w01}, W11 = {w11, w11};
    uint4v r;
#pragma unroll
    for (int j = 0; j < 4; ++j) {
        f32x2 s = W00 * bf2x2(c00[j]) + W10 * bf2x2(c10[j])
                + W01 * bf2x2(c01[j]) + W11 * bf2x2(c11[j]);
        r[j] = pack_bf2(s);
    }
    return r;
}

// ---------------------------------------------------------------------------
// Fused prep: blocks 0..1023 transpose x NCHW f32 -> NHWC bf16 (float4 loads,
// ushort8 stores); blocks 1024..1167 pack weight into MFMA B fragments.
// ---------------------------------------------------------------------------
__global__ __launch_bounds__(256) void dcl_prep(const float* __restrict__ x,
                                                const float* __restrict__ wgt,
                                                unsigned short* __restrict__ xt,
                                                unsigned short* __restrict__ wtb) {
    if (blockIdx.x < 1024) {
        __shared__ float tile[64][68];   // stride 68: float4-aligned, bank-benign
        int chunk = blockIdx.x;
        int b = chunk >> 8;
        int hw0 = (chunk & 255) * 64;
        int tid = threadIdx.x;           // 0..255
        int cg = tid >> 4;               // 0..15
        int tx4 = (tid & 15) * 4;        // 0,4,..,60
        const float* xb = x + (size_t)b * CH * HW + hw0;
#pragma unroll
        for (int pass = 0; pass < 4; ++pass) {
            int c = pass * 16 + cg;
            float4 v = *(const float4*)(xb + (size_t)c * HW + tx4);
            *(float4*)&tile[c][tx4] = v;
        }
        __syncthreads();
        unsigned short* xtb = xt + ((size_t)b << 20) + (size_t)hw0 * CH;
        int c8 = (tid & 7) * 8;
        int p0 = tid >> 3;               // 0..31
#pragma unroll
        for (int it = 0; it < 2; ++it) {
            int pxl = p0 + it * 32;
            ushort8v v;
#pragma unroll
            for (int j = 0; j < 8; ++j) v[j] = f2bf(tile[c8 + j][pxl]);
            *(ushort8v*)(xtb + (size_t)pxl * CH + c8) = v;
        }
    } else {
        // wpack: lane l of frag (ks,nt) holds B[k][n], k=ks*32+(l>>4)*8+j,
        // n=nt*16+(l&15), k=t*64+c.  addr: wtb[((ks*4+nt)*64+l)*8+j]
        int idx = (blockIdx.x - 1024) * 256 + threadIdx.x;   // 0..36863
        int j  = idx & 7;
        int l  = (idx >> 3) & 63;
        int nt = (idx >> 9) & 3;
        int ks = idx >> 11;
        int k = ks * 32 + ((l >> 4) * 8) + j;
        int n = nt * 16 + (l & 15);
        int c = k & 63;
        int t = k >> 6;
        wtb[idx] = f2bf(wgt[(n * CH + c) * KK + t]);
    }
}

// ---------------------------------------------------------------------------
// Main (R11 structure — best measured: 101.1 us total): block = 4 waves over
// a 16x4 px tile. Pixel tile + asymmetric halo (25x12 records, 38.4 KB ->
// 4 blocks/CU) staged to LDS once (coalesced, swizzled: record p rotated by
// (p&7)*16B so scattered ds_read_b128 are <=2-way conflicts = free).
// Out-of-halo offsets (P~1e-5/lane-tap) fall back to exec-masked global
// gathers. B fragments from global (L2-hot, coalesced). ONE barrier before
// the tap loop.
// Post-R12 note: M=32/wave (halved B traffic) measured WORSE (103.8) — in
// this latency-bound regime block-residency x in-flight depth beats L2-byte
// savings. Do not retry.
// ---------------------------------------------------------------------------
__global__ __launch_bounds__(256, 4) void dcl_main(
        const unsigned short* __restrict__ xt,   // [b][h][w][c] bf16
        const float* __restrict__ offset,
        const unsigned short* __restrict__ wtb,  // packed B fragments (72 KB)
        const float* __restrict__ bias,
        float* __restrict__ out) {
    __shared__ __align__(16) int smem[NREC * 32];   // 38400 B
    int tid = threadIdx.x;          // 0..255
    int lane = tid & 63;
    int wave = tid >> 6;            // 0..3

    // 16x4 pixel tile: 8 x-tiles, 32 y-tiles per image
    int b  = blockIdx.x >> 8;
    int t8 = blockIdx.x & 255;
    int x0 = (t8 & 7) << 4;
    int y0 = (t8 >> 3) << 2;
    int m = lane & 15;
    int quad = lane >> 4;
    int qoff = quad * 16;
    int y = y0 + wave;              // this wave's pixel row
    int pm = x0 + m;                // this lane's pixel x

    const char* xtb = (const char*)xt;
    const char* xim = xtb + (((size_t)b << 14) << 7);   // image base (bytes)
    const float* ob = offset + (((size_t)(b * 18)) << 14) + (y << 7) + pm;
    float pxf = (float)pm;
    float pyf = (float)y;

    // ---- preload all 18 offset values ----
    float oxv[9], oyv[9];
#pragma unroll
    for (int t = 0; t < 9; ++t) {
        oxv[t] = ob[(size_t)(2 * t) << 14];
        oyv[t] = ob[(size_t)(2 * t + 1) << 14];
    }

    // ---- stage pixel tile + halo into LDS (coalesced, swizzled) ----
    uint4v* sv = (uint4v*)smem;
#pragma unroll
    for (int i = 0; i < 10; ++i) {
        int id = tid + i * 256;
        if (id < NCHUNK) {
            int p = id >> 3, sub = id & 7;
            int r = p / TW, col = p - r * TW;
            int sy = min(max(y0 - HYT + r, 0), HH - 1);
            int sx = min(max(x0 - HX + col, 0), WW - 1);
            uint4v v = *(const uint4v*)(xim + (((sy << 7) + sx) << 7) + (sub << 4));
            sv[p * 8 + ((sub + (p & 7)) & 7)] = v;
        }
    }

    f32x4 acc[4];
#pragma unroll
    for (int i = 0; i < 4; ++i) acc[i] = (f32x4)(0.f);

    const short8* bfrags = (const short8*)wtb;

    __syncthreads();                // tile visible; only pre-epilogue barrier

    // ---- 9 taps, fully unrolled, barrier-free ----
#pragma unroll
    for (int t = 0; t < 9; ++t) {
        float fx = pxf + oxv[t];
        float fy = pyf + oyv[t];
        float x0f = floorf(fx), y0f = floorf(fy);
        float wx1 = fx - x0f, wy1 = fy - y0f;
        float wx0 = 1.0f - wx1, wy0 = 1.0f - wy1;
        int ix0 = (int)x0f, iy0 = (int)y0f;
        int ix1 = ix0 + 1, iy1 = iy0 + 1;
        bool vx0 = (unsigned)ix0 < (unsigned)WW;
        bool vx1 = (unsigned)ix1 < (unsigned)WW;
        bool vy0 = (unsigned)iy0 < (unsigned)HH;
        bool vy1 = (unsigned)iy1 < (unsigned)HH;
        float w00 = (vx0 && vy0) ? wx0 * wy0 : 0.0f;
        float w10 = (vx1 && vy0) ? wx1 * wy0 : 0.0f;
        float w01 = (vx0 && vy1) ? wx0 * wy1 : 0.0f;
        float w11 = (vx1 && vy1) ? wx1 * wy1 : 0.0f;
        int cx0 = min(max(ix0, 0), WW - 1), cx1 = min(max(ix1, 0), WW - 1);
        int cy0 = min(max(iy0, 0), HH - 1), cy1 = min(max(iy1, 0), HH - 1);

        // tile-local coords (image-clamped coords match the clamped staging,
        // so image-edge clamping never triggers the fallback)
        int lc0 = cx0 - x0 + HX, lc1 = cx1 - x0 + HX;
        int lr0 = cy0 - y0 + HYT, lr1 = cy1 - y0 + HYT;
        bool oof = ((unsigned)lc0 > (TW - 1)) | ((unsigned)lc1 > (TW - 1)) |
                   ((unsigned)lr0 > (TH - 1)) | ((unsigned)lr1 > (TH - 1));
        int sc0 = min(max(lc0, 0), TW - 1), sc1 = min(max(lc1, 0), TW - 1);
        int sr0 = min(max(lr0, 0), TH - 1), sr1 = min(max(lr1, 0), TH - 1);
        int p00 = sr0 * TW + sc0, p10 = sr0 * TW + sc1;
        int p01 = sr1 * TW + sc0, p11 = sr1 * TW + sc1;

        uint4v c00a = sv[p00 * 8 + ((quad + (p00 & 7)) & 7)];
        uint4v c00b = sv[p00 * 8 + ((quad + 4 + (p00 & 7)) & 7)];
        uint4v c10a = sv[p10 * 8 + ((quad + (p10 & 7)) & 7)];
        uint4v c10b = sv[p10 * 8 + ((quad + 4 + (p10 & 7)) & 7)];
        uint4v c01a = sv[p01 * 8 + ((quad + (p01 & 7)) & 7)];
        uint4v c01b = sv[p01 * 8 + ((quad + 4 + (p01 & 7)) & 7)];
        uint4v c11a = sv[p11 * 8 + ((quad + (p11 & 7)) & 7)];
        uint4v c11b = sv[p11 * 8 + ((quad + 4 + (p11 & 7)) & 7)];

        if (__builtin_expect(oof, 0)) {   // rare: genuinely large offsets
            int base = b << 14;
            int o00 = ((base + (cy0 << 7) + cx0) << 7) + qoff;
            int o10 = ((base + (cy0 << 7) + cx1) << 7) + qoff;
            int o01 = ((base + (cy1 << 7) + cx0) << 7) + qoff;
            int o11 = ((base + (cy1 << 7) + cx1) << 7) + qoff;
            c00a = *(const uint4v*)(xtb + o00);
            c00b = *(const uint4v*)(xtb + o00 + 64);
            c10a = *(const uint4v*)(xtb + o10);
            c10b = *(const uint4v*)(xtb + o10 + 64);
            c01a = *(const uint4v*)(xtb + o01);
            c01b = *(const uint4v*)(xtb + o01 + 64);
            c11a = *(const uint4v*)(xtb + o11);
            c11b = *(const uint4v*)(xtb + o11 + 64);
        }

        uint4v ra = combine4(c00a, c10a, c01a, c11a, w00, w10, w01, w11);
        uint4v rb = combine4(c00b, c10b, c01b, c11b, w00, w10, w01, w11);
        short8 aa = __builtin_bit_cast(short8, ra);
        short8 ab = __builtin_bit_cast(short8, rb);

        int ks = 2 * t;
#pragma unroll
        for (int nt = 0; nt < 4; ++nt)
            acc[nt] = __builtin_amdgcn_mfma_f32_16x16x32_bf16(
                aa, bfrags[(ks * 4 + nt) * 64 + lane], acc[nt], 0, 0, 0);
#pragma unroll
        for (int nt = 0; nt < 4; ++nt)
            acc[nt] = __builtin_amdgcn_mfma_f32_16x16x32_bf16(
                ab, bfrags[((ks + 1) * 4 + nt) * 64 + lane], acc[nt], 0, 0, 0);
    }

    // ---- epilogue: C tiles -> LDS (reuse tile area), coalesced store ----
    __syncthreads();
    float* o_w = (float*)smem + wave * 1040;    // [x_local][o], stride 65
#pragma unroll
    for (int nt = 0; nt < 4; ++nt)
#pragma unroll
        for (int reg = 0; reg < 4; ++reg)
            o_w[(quad * 4 + reg) * 65 + nt * 16 + m] = acc[nt][reg];
    __syncthreads();

    const float* os = (const float*)smem;
#pragma unroll
    for (int j = tid; j < 64 * 64; j += 256) {
        int o = j >> 6;                  // wave-uniform per iteration
        int p = j & 63;
        int row = p >> 4, xx = p & 15;
        float v = os[row * 1040 + xx * 65 + o] + bias[o];
        out[(((size_t)(b * OH + o)) << 14) + ((y0 + row) << 7) + x0 + xx] = v;
    }
}

extern "C" void kernel_launch(void* const* d_in, const int* in_sizes, int n_in,
                              void* d_out, int out_size, void* d_ws, size_t ws_size,
                              hipStream_t stream) {
    const float* x      = (const float*)d_in[0];
    const float* offset = (const float*)d_in[1];
    const float* weight = (const float*)d_in[2];
    const float* bias   = (const float*)d_in[3];
    float* out = (float*)d_out;

    unsigned short* xt  = (unsigned short*)d_ws;                           // 8.39 MB
    unsigned short* wtb = (unsigned short*)((char*)d_ws + (size_t)BH * HW * CH * 2);

    dcl_prep<<<1024 + 144, 256, 0, stream>>>(x, weight, xt, wtb);
    dcl_main<<<(BH * HW) / 64, 256, 0, stream>>>(xt, offset, wtb, bias, out);
}